// Round 1
// baseline (113.626 us; speedup 1.0000x reference)
//
#include <hip/hip_runtime.h>

#define NQ_ 30000
#define NC_ 16
#define C_  128
#define NS_ 8192
#define QB  16
#define NBLK (NQ_/QB)   // 1875

typedef __attribute__((ext_vector_type(4))) float  f32x4;
typedef __attribute__((ext_vector_type(4))) short  s16x4;
typedef __attribute__((ext_vector_type(8))) short  s16x8;

// workspace layout (float offsets)
#define WS_PART  0         // 16 cls * 16 chunks * 128 = 32768
#define WS_PCNT  32768     // 256
#define WS_PROTO 33024     // 2048
#define WS_PN    35072     // 2048
#define WS_T     37120     // 2048  (protos @ Wp + b1)

__device__ inline short f2bf(float x){           // round-to-nearest-even bf16
  unsigned u = __float_as_uint(x);
  u += 0x7fffu + ((u >> 16) & 1u);
  return (short)(u >> 16);
}

// ---- prototypes: deterministic fixed-order partial sums ----
__global__ __launch_bounds__(128) void proto_part(const float* __restrict__ sf,
                                                  const int* __restrict__ lbl,
                                                  float* __restrict__ ws){
  const int cls = blockIdx.x >> 4;
  const int ch  = blockIdx.x & 15;
  const int c   = threadIdx.x;
  const int r0  = ch * (NS_/16);
  float s = 0.f; int cnt = 0;
  #pragma unroll 4
  for (int r = r0; r < r0 + NS_/16; ++r){
    if (lbl[r] == cls){ s += sf[(size_t)r*C_ + c]; ++cnt; }
  }
  ws[WS_PART + (cls*16 + ch)*C_ + c] = s;
  if (c == 0) ws[WS_PCNT + cls*16 + ch] = (float)cnt;
}

__global__ __launch_bounds__(256) void proto_finalize(float* __restrict__ ws){
  __shared__ float p[NC_][C_];
  __shared__ float rn[NC_];
  const int t = threadIdx.x;
  for (int idx = t; idx < NC_*C_; idx += 256){
    int n = idx >> 7, c = idx & 127;
    float s = 0.f, cnt = 0.f;
    #pragma unroll
    for (int ch = 0; ch < 16; ++ch) s   += ws[WS_PART + (n*16+ch)*C_ + c];
    #pragma unroll
    for (int ch = 0; ch < 16; ++ch) cnt += ws[WS_PCNT + n*16 + ch];
    float pv = (cnt > 0.f) ? s / fmaxf(cnt, 1.f) : 0.f;
    p[n][c] = pv;
    ws[WS_PROTO + idx] = pv;
  }
  __syncthreads();
  if (t < NC_){
    float s = 0.f;
    #pragma unroll 4
    for (int c = 0; c < C_; ++c) s = fmaf(p[t][c], p[t][c], s);
    rn[t] = 1.f / fmaxf(sqrtf(s), 1e-8f);
  }
  __syncthreads();
  for (int idx = t; idx < NC_*C_; idx += 256){
    int n = idx >> 7;
    ws[WS_PN + idx] = p[n][idx & 127] * rn[n];
  }
}

__global__ __launch_bounds__(128) void proto_tmat(const float* __restrict__ W1,
                                                  const float* __restrict__ b1,
                                                  float* __restrict__ ws){
  __shared__ float p[C_];
  const int n = blockIdx.x, h = threadIdx.x;
  p[h] = ws[WS_PROTO + n*C_ + h];
  __syncthreads();
  float acc = b1[h];
  #pragma unroll 4
  for (int c = 0; c < C_; ++c) acc = fmaf(p[c], W1[(C_ + c)*C_ + h], acc);
  ws[WS_T + n*C_ + h] = acc;
}

// ---- fused main: qW & cos via MFMA, H generated in fragment order, sim via MFMA ----
__global__ __launch_bounds__(512) void fused_main(const float* __restrict__ qfeat,
                                                  const float* __restrict__ W1,
                                                  const float* __restrict__ W2,
                                                  const float* __restrict__ b2,
                                                  const float* __restrict__ ws,
                                                  float* __restrict__ out){
  __shared__ float qf[QB][132];
  __shared__ float qw[QB][132];
  __shared__ float tl[NC_][132];
  __shared__ float cosl[QB][NC_];
  __shared__ float rqn[QB];
  __shared__ float wcl[C_];
  __shared__ __align__(16) short hfrag[8*2048];   // 8 queries * (64 lanes * 32 bf16)

  const int t    = threadIdx.x;
  const int lane = t & 63;
  const int wv   = t >> 6;            // 8 waves, wave = one 16-wide o-tile
  const int qbase = blockIdx.x * QB;
  float* out_cos = out + (size_t)NQ_ * NC_ * C_;

  // stage qf (16x128), t-matrix, Wc
  {
    int idx = t * 4; int q = idx >> 7; int c = idx & 127;
    *(f32x4*)&qf[q][c] = *(const f32x4*)(qfeat + (size_t)qbase*C_ + idx);
    *(f32x4*)&tl[q][c] = *(const f32x4*)(ws + WS_T + idx);
    if (t < 32) *(f32x4*)&wcl[t*4] = *(const f32x4*)(W1 + 2*C_*C_ + t*4);
  }
  __syncthreads();

  // 1/max(||q||, eps)
  if (t < 128){
    int q = t >> 3; int c0 = (t & 7) * 16;
    float s = 0.f;
    #pragma unroll
    for (int m = 0; m < 16; ++m){ float v = qf[q][c0+m]; s = fmaf(v, v, s); }
    s += __shfl_xor(s, 1); s += __shfl_xor(s, 2); s += __shfl_xor(s, 4);
    if ((t & 7) == 0) rqn[q] = 1.f / fmaxf(sqrtf(s), 1e-8f);
  }

  const int fr = lane & 15;   // tile row/col index
  const int fg = lane >> 4;   // k-group
  const int ocol = wv*16 + fr;

  // A-fragments of qf (row = query), B-fragments of W2 and Wq (col = ocol)
  s16x8 qfr[4], w2f[4], wqf[4];
  #pragma unroll
  for (int ks = 0; ks < 4; ++ks){
    const int c0 = ks*32 + fg*8;
    f32x4 a = *(const f32x4*)&qf[fr][c0];
    f32x4 b = *(const f32x4*)&qf[fr][c0+4];
    s16x8 v;
    v[0]=f2bf(a[0]); v[1]=f2bf(a[1]); v[2]=f2bf(a[2]); v[3]=f2bf(a[3]);
    v[4]=f2bf(b[0]); v[5]=f2bf(b[1]); v[6]=f2bf(b[2]); v[7]=f2bf(b[3]);
    qfr[ks] = v;
    #pragma unroll
    for (int i = 0; i < 8; ++i){
      const int k = c0 + i;
      w2f[ks][i] = f2bf(W2[k*C_ + ocol]);
      wqf[ks][i] = f2bf(W1[k*C_ + ocol]);   // Wq = W1 rows [0,128)
    }
  }
  const float b2v = b2[ocol];
  __syncthreads();   // rqn ready

  // qW = qf @ Wq  (D: row=(fg*4+r)=query, col=fr -> h=ocol)
  {
    f32x4 dq = {0.f,0.f,0.f,0.f};
    #pragma unroll
    for (int ks = 0; ks < 4; ++ks)
      dq = __builtin_amdgcn_mfma_f32_16x16x32_bf16(qfr[ks], wqf[ks], dq, 0,0,0);
    #pragma unroll
    for (int r = 0; r < 4; ++r) qw[fg*4 + r][ocol] = dq[r];
  }
  // cos = (qf @ pn^T) * rqn   (wave 0 only)
  if (wv == 0){
    s16x8 pnf[4];
    #pragma unroll
    for (int ks = 0; ks < 4; ++ks){
      #pragma unroll
      for (int i = 0; i < 8; ++i)
        pnf[ks][i] = f2bf(ws[WS_PN + fr*C_ + ks*32 + fg*8 + i]);
    }
    f32x4 dc = {0.f,0.f,0.f,0.f};
    #pragma unroll
    for (int ks = 0; ks < 4; ++ks)
      dc = __builtin_amdgcn_mfma_f32_16x16x32_bf16(qfr[ks], pnf[ks], dc, 0,0,0);
    #pragma unroll
    for (int r = 0; r < 4; ++r){
      const int q = fg*4 + r;
      const float cv = dc[r] * rqn[q];
      cosl[q][fr] = cv;
      out_cos[(size_t)(qbase + q)*NC_ + fr] = cv;
    }
  }
  __syncthreads();   // qw, cosl ready

  // phase-A per-thread constants: thread t generates 4 H elements per query
  // frag elem (lane=l, kstep=ksA, i in [ii0,ii0+4)) for class na, k = k0..k0+3
  const int sel = t >> 6;
  const int na  = lane & 15;
  const int ga  = lane >> 4;
  const int ksA = sel >> 1;
  const int ii0 = (sel & 1) * 4;
  const int k0  = ksA*32 + ga*8 + ii0;
  const f32x4 t4  = *(const f32x4*)&tl[na][k0];
  const f32x4 wc4 = *(const f32x4*)&wcl[k0];

  #pragma unroll
  for (int chunk = 0; chunk < 2; ++chunk){
    const int q0 = chunk * 8;
    // phase A: H = relu(qW + t_n + cos*Wc) -> bf16 fragments in LDS
    #pragma unroll
    for (int qq = 0; qq < 8; ++qq){
      const int q = q0 + qq;
      f32x4 qw4 = *(const f32x4*)&qw[q][k0];
      const float cv = cosl[q][na];
      s16x4 hv;
      #pragma unroll
      for (int j = 0; j < 4; ++j){
        float h = fmaf(cv, wc4[j], qw4[j] + t4[j]);
        hv[j] = f2bf(fmaxf(h, 0.f));
      }
      *(s16x4*)&hfrag[qq*2048 + ksA*512 + lane*8 + ii0] = hv;
    }
    __syncthreads();
    // phase B: sim = H @ W2 + b2, one 16x16 tile per wave per query
    #pragma unroll
    for (int qq = 0; qq < 8; ++qq){
      s16x8 a0 = *(const s16x8*)&hfrag[qq*2048 +   0 + lane*8];
      s16x8 a1 = *(const s16x8*)&hfrag[qq*2048 + 512 + lane*8];
      s16x8 a2 = *(const s16x8*)&hfrag[qq*2048 + 1024 + lane*8];
      s16x8 a3 = *(const s16x8*)&hfrag[qq*2048 + 1536 + lane*8];
      f32x4 acc = {b2v, b2v, b2v, b2v};
      acc = __builtin_amdgcn_mfma_f32_16x16x32_bf16(a0, w2f[0], acc, 0,0,0);
      acc = __builtin_amdgcn_mfma_f32_16x16x32_bf16(a1, w2f[1], acc, 0,0,0);
      acc = __builtin_amdgcn_mfma_f32_16x16x32_bf16(a2, w2f[2], acc, 0,0,0);
      acc = __builtin_amdgcn_mfma_f32_16x16x32_bf16(a3, w2f[3], acc, 0,0,0);
      const size_t qout = (size_t)(qbase + q0 + qq) * (NC_*C_);
      #pragma unroll
      for (int r = 0; r < 4; ++r)
        out[qout + (fg*4 + r)*C_ + ocol] = acc[r];
    }
    __syncthreads();
  }
}

extern "C" void kernel_launch(void* const* d_in, const int* in_sizes, int n_in,
                              void* d_out, int out_size, void* d_ws, size_t ws_size,
                              hipStream_t stream){
  const float* sf  = (const float*)d_in[0];
  const int*   lbl = (const int*)  d_in[1];
  const float* qf  = (const float*)d_in[2];
  const float* W1  = (const float*)d_in[3];
  const float* b1  = (const float*)d_in[4];
  const float* W2  = (const float*)d_in[5];
  const float* b2  = (const float*)d_in[6];
  float* ws  = (float*)d_ws;
  float* out = (float*)d_out;

  proto_part<<<256, 128, 0, stream>>>(sf, lbl, ws);
  proto_finalize<<<1, 256, 0, stream>>>(ws);
  proto_tmat<<<NC_, 128, 0, stream>>>(W1, b1, ws);
  fused_main<<<NBLK, 512, 0, stream>>>(qf, W1, W2, b2, ws, out);
}

// Round 2
// 104.481 us; speedup vs baseline: 1.0875x; 1.0875x over previous
//
#include <hip/hip_runtime.h>

#define NQ_ 30000
#define NC_ 16
#define C_  128
#define NS_ 8192
#define QB  16
#define NBLK (NQ_/QB)   // 1875

typedef __attribute__((ext_vector_type(4))) float  f32x4;
typedef __attribute__((ext_vector_type(4))) short  s16x4;
typedef __attribute__((ext_vector_type(8))) short  s16x8;

// workspace layout (float offsets)
#define WS_PART  0         // 16 cls * 16 chunks * 128 = 32768
#define WS_PCNT  32768     // 256
#define WS_PROTO 33024     // 2048
#define WS_PN    35072     // 2048
#define WS_T     37120     // 2048  (protos @ Wp + b1)
#define WS_PACK  39168     // shorts from here: W2frag[16384] Wqfrag[16384] pnfrag[2048]

__device__ inline short f2bf(float x){           // round-to-nearest-even bf16
  unsigned u = __float_as_uint(x);
  u += 0x7fffu + ((u >> 16) & 1u);
  return (short)(u >> 16);
}

// ---- prototypes: deterministic fixed-order partial sums ----
__global__ __launch_bounds__(128) void proto_part(const float* __restrict__ sf,
                                                  const int* __restrict__ lbl,
                                                  float* __restrict__ ws){
  const int cls = blockIdx.x >> 4;
  const int ch  = blockIdx.x & 15;
  const int c   = threadIdx.x;
  const int r0  = ch * (NS_/16);
  float s = 0.f; int cnt = 0;
  #pragma unroll 4
  for (int r = r0; r < r0 + NS_/16; ++r){
    if (lbl[r] == cls){ s += sf[(size_t)r*C_ + c]; ++cnt; }
  }
  ws[WS_PART + (cls*16 + ch)*C_ + c] = s;
  if (c == 0) ws[WS_PCNT + cls*16 + ch] = (float)cnt;
}

__global__ __launch_bounds__(256) void proto_finalize(float* __restrict__ ws){
  __shared__ float p[NC_][C_];
  __shared__ float rn[NC_];
  const int t = threadIdx.x;
  for (int idx = t; idx < NC_*C_; idx += 256){
    int n = idx >> 7, c = idx & 127;
    float s = 0.f, cnt = 0.f;
    #pragma unroll
    for (int ch = 0; ch < 16; ++ch) s   += ws[WS_PART + (n*16+ch)*C_ + c];
    #pragma unroll
    for (int ch = 0; ch < 16; ++ch) cnt += ws[WS_PCNT + n*16 + ch];
    float pv = (cnt > 0.f) ? s / fmaxf(cnt, 1.f) : 0.f;
    p[n][c] = pv;
    ws[WS_PROTO + idx] = pv;
  }
  __syncthreads();
  if (t < NC_){
    float s = 0.f;
    #pragma unroll 4
    for (int c = 0; c < C_; ++c) s = fmaf(p[t][c], p[t][c], s);
    rn[t] = 1.f / fmaxf(sqrtf(s), 1e-8f);
  }
  __syncthreads();
  for (int idx = t; idx < NC_*C_; idx += 256){
    int n = idx >> 7;
    ws[WS_PN + idx] = p[n][idx & 127] * rn[n];
  }
}

__global__ __launch_bounds__(128) void proto_tmat(const float* __restrict__ W1,
                                                  const float* __restrict__ b1,
                                                  float* __restrict__ ws){
  __shared__ float p[C_];
  const int n = blockIdx.x, h = threadIdx.x;
  p[h] = ws[WS_PROTO + n*C_ + h];
  __syncthreads();
  float acc = b1[h];
  #pragma unroll 4
  for (int c = 0; c < C_; ++c) acc = fmaf(p[c], W1[(C_ + c)*C_ + h], acc);
  ws[WS_T + n*C_ + h] = acc;
}

// ---- pack W2 / Wq / pn into bf16 MFMA B-fragment order ----
// frag layout: short index ((wv*4+ks)*64 + lane)*8 + i  maps to
//   k = ks*32 + ((lane>>4)&3)*8 + i,  col = wv*16 + (lane&15)
__global__ __launch_bounds__(512) void weight_pack(const float* __restrict__ W1,
                                                   const float* __restrict__ W2,
                                                   float* __restrict__ ws){
  const int g = blockIdx.x * 512 + threadIdx.x;   // grid 68 -> 34816 exact
  short* pack = (short*)(ws + WS_PACK);
  const int gg   = g & 16383;
  const int i    = gg & 7;
  const int lane = (gg >> 3) & 63;
  const int ks   = (gg >> 9) & 3;
  const int wv   = gg >> 11;
  const int k    = ks*32 + ((lane >> 4) & 3)*8 + i;
  const int col  = wv*16 + (lane & 15);
  if (g < 16384){
    pack[g] = f2bf(W2[k*C_ + col]);
  } else if (g < 32768){
    pack[g] = f2bf(W1[k*C_ + col]);                 // Wq = W1 rows [0,128)
  } else {                                          // g in [32768, 34816): wv==0
    pack[g] = f2bf(ws[WS_PN + (lane & 15)*C_ + k]); // pn^T B-frags
  }
}

// ---- fused main ----
__global__ __launch_bounds__(512) void fused_main(const float* __restrict__ qfeat,
                                                  const float* __restrict__ W1,
                                                  const float* __restrict__ b2,
                                                  const float* __restrict__ ws,
                                                  float* __restrict__ out){
  __shared__ __align__(16) char un[16384];   // qfs[16][132] f32, then hfrag[4*2048] bf16
  __shared__ float qw[QB][132];
  __shared__ float tl16[NC_][132];
  __shared__ float cosl[QB][NC_];
  __shared__ float rqn[QB];
  __shared__ float wcl[C_];

  float (*qfs)[132] = (float(*)[132])un;
  short* hfrag = (short*)un;

  const int t    = threadIdx.x;
  const int lane = t & 63;
  const int wv   = t >> 6;
  const int qbase = blockIdx.x * QB;
  float* out_cos = out + (size_t)NQ_ * NC_ * C_;
  const short* pack = (const short*)(ws + WS_PACK);

  // stage qf (16x128), t-matrix, Wc — all coalesced
  {
    int idx = t * 4; int q = idx >> 7; int c = idx & 127;
    *(f32x4*)&qfs[q][c]  = *(const f32x4*)(qfeat + (size_t)qbase*C_ + idx);
    *(f32x4*)&tl16[q][c] = *(const f32x4*)(ws + WS_T + idx);
    if (t < 32) *(f32x4*)&wcl[t*4] = *(const f32x4*)(W1 + 2*C_*C_ + t*4);
  }
  __syncthreads();

  // 1/max(||q||, eps)
  if (t < 128){
    int q = t >> 3; int c0 = (t & 7) * 16;
    float s = 0.f;
    #pragma unroll
    for (int m = 0; m < 16; ++m){ float v = qfs[q][c0+m]; s = fmaf(v, v, s); }
    s += __shfl_xor(s, 1); s += __shfl_xor(s, 2); s += __shfl_xor(s, 4);
    if ((t & 7) == 0) rqn[q] = 1.f / fmaxf(sqrtf(s), 1e-8f);
  }

  const int fr = lane & 15;
  const int fg = lane >> 4;
  const int ocol = wv*16 + fr;

  // A-fragments of qf; B-fragments of W2/Wq loaded COALESCED from pack
  s16x8 qfr[4], w2f[4], wqf[4];
  #pragma unroll
  for (int ks = 0; ks < 4; ++ks){
    const int c0 = ks*32 + fg*8;
    f32x4 a = *(const f32x4*)&qfs[fr][c0];
    f32x4 b = *(const f32x4*)&qfs[fr][c0+4];
    s16x8 v;
    v[0]=f2bf(a[0]); v[1]=f2bf(a[1]); v[2]=f2bf(a[2]); v[3]=f2bf(a[3]);
    v[4]=f2bf(b[0]); v[5]=f2bf(b[1]); v[6]=f2bf(b[2]); v[7]=f2bf(b[3]);
    qfr[ks] = v;
    w2f[ks] = *(const s16x8*)&pack[((wv*4 + ks)*64 + lane)*8];
    wqf[ks] = *(const s16x8*)&pack[16384 + ((wv*4 + ks)*64 + lane)*8];
  }
  const float b2v = b2[ocol];
  __syncthreads();   // rqn ready; all qfs reads done (un reused as hfrag after next sync)

  // qW = qf @ Wq
  {
    f32x4 dq = {0.f,0.f,0.f,0.f};
    #pragma unroll
    for (int ks = 0; ks < 4; ++ks)
      dq = __builtin_amdgcn_mfma_f32_16x16x32_bf16(qfr[ks], wqf[ks], dq, 0,0,0);
    #pragma unroll
    for (int r = 0; r < 4; ++r) qw[fg*4 + r][ocol] = dq[r];
  }
  // cos = (qf @ pn^T) * rqn   (wave 0)
  if (wv == 0){
    s16x8 pnf[4];
    #pragma unroll
    for (int ks = 0; ks < 4; ++ks)
      pnf[ks] = *(const s16x8*)&pack[32768 + (ks*64 + lane)*8];
    f32x4 dc = {0.f,0.f,0.f,0.f};
    #pragma unroll
    for (int ks = 0; ks < 4; ++ks)
      dc = __builtin_amdgcn_mfma_f32_16x16x32_bf16(qfr[ks], pnf[ks], dc, 0,0,0);
    #pragma unroll
    for (int r = 0; r < 4; ++r){
      const int q = fg*4 + r;
      const float cv = dc[r] * rqn[q];
      cosl[q][fr] = cv;
      out_cos[(size_t)(qbase + q)*NC_ + fr] = cv;
    }
  }
  __syncthreads();   // qw, cosl ready; qfs dead -> hfrag live

  // phase-A constants: wave wv handles (ksA, ii0); lane -> (class na, k-group ga)
  const int na  = lane & 15;
  const int ga  = lane >> 4;
  const int ksA = wv >> 1;
  const int ii0 = (wv & 1) * 4;
  const int k0  = ksA*32 + ga*8 + ii0;
  const f32x4 t4  = *(const f32x4*)&tl16[na][k0];
  const f32x4 wc4 = *(const f32x4*)&wcl[k0];

  #pragma unroll
  for (int chunk = 0; chunk < 4; ++chunk){
    const int q0 = chunk * 4;
    // phase A: H = relu(qW + t_n + cos*Wc) -> bf16 fragments in LDS
    #pragma unroll
    for (int qq = 0; qq < 4; ++qq){
      const int q = q0 + qq;
      f32x4 qw4 = *(const f32x4*)&qw[q][k0];
      const float cv = cosl[q][na];
      s16x4 hv;
      #pragma unroll
      for (int j = 0; j < 4; ++j){
        float h = fmaf(cv, wc4[j], qw4[j] + t4[j]);
        hv[j] = f2bf(fmaxf(h, 0.f));
      }
      *(s16x4*)&hfrag[qq*2048 + ksA*512 + lane*8 + ii0] = hv;
    }
    __syncthreads();
    // phase B: sim = H @ W2 + b2
    #pragma unroll
    for (int qq = 0; qq < 4; ++qq){
      s16x8 a0 = *(const s16x8*)&hfrag[qq*2048 +    0 + lane*8];
      s16x8 a1 = *(const s16x8*)&hfrag[qq*2048 +  512 + lane*8];
      s16x8 a2 = *(const s16x8*)&hfrag[qq*2048 + 1024 + lane*8];
      s16x8 a3 = *(const s16x8*)&hfrag[qq*2048 + 1536 + lane*8];
      f32x4 acc = {b2v, b2v, b2v, b2v};
      acc = __builtin_amdgcn_mfma_f32_16x16x32_bf16(a0, w2f[0], acc, 0,0,0);
      acc = __builtin_amdgcn_mfma_f32_16x16x32_bf16(a1, w2f[1], acc, 0,0,0);
      acc = __builtin_amdgcn_mfma_f32_16x16x32_bf16(a2, w2f[2], acc, 0,0,0);
      acc = __builtin_amdgcn_mfma_f32_16x16x32_bf16(a3, w2f[3], acc, 0,0,0);
      const size_t qout = (size_t)(qbase + q0 + qq) * (NC_*C_);
      #pragma unroll
      for (int r = 0; r < 4; ++r)
        out[qout + (fg*4 + r)*C_ + ocol] = acc[r];
    }
    __syncthreads();
  }
}

extern "C" void kernel_launch(void* const* d_in, const int* in_sizes, int n_in,
                              void* d_out, int out_size, void* d_ws, size_t ws_size,
                              hipStream_t stream){
  const float* sf  = (const float*)d_in[0];
  const int*   lbl = (const int*)  d_in[1];
  const float* qf  = (const float*)d_in[2];
  const float* W1  = (const float*)d_in[3];
  const float* b1  = (const float*)d_in[4];
  const float* W2  = (const float*)d_in[5];
  const float* b2  = (const float*)d_in[6];
  float* ws  = (float*)d_ws;
  float* out = (float*)d_out;

  proto_part<<<256, 128, 0, stream>>>(sf, lbl, ws);
  proto_finalize<<<1, 256, 0, stream>>>(ws);
  proto_tmat<<<NC_, 128, 0, stream>>>(W1, b1, ws);
  weight_pack<<<68, 512, 0, stream>>>(W1, W2, ws);
  fused_main<<<NBLK, 512, 0, stream>>>(qf, W1, b2, ws, out);
}